// Round 12
// baseline (300.413 us; speedup 1.0000x reference)
//
#include <hip/hip_runtime.h>
#include <hip/hip_bf16.h>
#include <math.h>

// GNNStack: 3x GAT(heads=1, hid=64) + relu, then 64->64, 64->47, log_softmax.
//  - CSR build via two-level counting sort; count/scatter at 1024 blocks
//    (R11: 256 blocks = 7% occupancy = 40us latency-bound scatter).
//  - LIN/POST: MFMA 16x16x32 bf16, all inter-layer tensors bf16.
//  - alpha for layers 1,2 FUSED into agg epilogue via associativity:
//    alpha_{l+1} = relu_out . (W_{l+1} @ att) + b.att  (folded vectors
//    precomputed by a tiny prep kernel). Only 8 shfl/wave lifetime — the
//    R9 failure (128 bpermute per tile iter) doesn't apply.
//  - AGG: 16-lane group = one node; LDS pair buffer; 8-deep gather batches
//    (~2.5 TB/s HBM, near the random-128B floor).

#define IN_DIM 128
#define HID 64
#define OUT_DIM 47
#define NEG_SLOPE 0.2f
#define EPS 1e-16f
#define BBITS 10
#define BN 1024
#define NBUCK_MAX 128

typedef short bf16x8 __attribute__((ext_vector_type(8)));
typedef float f32x4 __attribute__((ext_vector_type(4)));

__device__ __forceinline__ float bflo(unsigned int d) {
    union { unsigned int i; float f; } c;
    c.i = d << 16;
    return c.f;
}
__device__ __forceinline__ float bfhi(unsigned int d) {
    union { unsigned int i; float f; } c;
    c.i = d & 0xffff0000u;
    return c.f;
}
__device__ __forceinline__ ushort f2bf(float f) {
    __hip_bfloat16 b = __float2bfloat16(f);
    return *(ushort*)&b;
}

// ---- CSR build ----
__global__ __launch_bounds__(256) void bucket_count_kernel(const int* __restrict__ dst,
                                                           int* __restrict__ bcnt,
                                                           int e, int nbuck) {
    __shared__ int h[NBUCK_MAX];
    int tid = threadIdx.x;
    if (tid < nbuck) h[tid] = 0;
    __syncthreads();
    int chunk = (e + gridDim.x - 1) / gridDim.x;
    int beg = blockIdx.x * chunk, end = min(e, beg + chunk);
    for (int i = beg + tid; i < end; i += 256) atomicAdd(&h[dst[i] >> BBITS], 1);
    __syncthreads();
    if (tid < nbuck && h[tid]) atomicAdd(&bcnt[tid], h[tid]);
}

__global__ void bucket_scan_kernel(const int* __restrict__ bcnt, int* __restrict__ bbase,
                                   int* __restrict__ bfill, int nbuck) {
    if (threadIdx.x == 0 && blockIdx.x == 0) {
        int run = 0;
        for (int i = 0; i < nbuck; i++) { bbase[i] = run; bfill[i] = run; run += bcnt[i]; }
        bbase[nbuck] = run;
    }
}

__global__ __launch_bounds__(256) void bucket_scatter_kernel(const int* __restrict__ src,
                                                             const int* __restrict__ dst,
                                                             int* __restrict__ bfill,
                                                             int2* __restrict__ stg,
                                                             int e, int nbuck) {
    __shared__ int lcnt[NBUCK_MAX], lfill[NBUCK_MAX];
    int tid = threadIdx.x;
    if (tid < nbuck) lcnt[tid] = 0;
    __syncthreads();
    int chunk = (e + gridDim.x - 1) / gridDim.x;
    int beg = blockIdx.x * chunk, end = min(e, beg + chunk);
    for (int i = beg + tid; i < end; i += 256) atomicAdd(&lcnt[dst[i] >> BBITS], 1);
    __syncthreads();
    if (tid < nbuck) lfill[tid] = lcnt[tid] ? atomicAdd(&bfill[tid], lcnt[tid]) : 0;
    __syncthreads();
    for (int i = beg + tid; i < end; i += 256) {
        int d = dst[i];
        int p = atomicAdd(&lfill[d >> BBITS], 1);
        stg[p] = make_int2(src[i], d);
    }
}

__global__ __launch_bounds__(1024) void bucket_place_kernel(const int2* __restrict__ stg,
                                                            const int* __restrict__ bbase,
                                                            int* __restrict__ rowptr,
                                                            int* __restrict__ col,
                                                            int n, int e) {
    __shared__ int lcnt[BN];
    __shared__ int lscan[BN];
    __shared__ int lfill[BN];
    int tid = threadIdx.x, b = blockIdx.x;
    int node0 = b << BBITS;
    int ebeg = bbase[b], eend = bbase[b + 1];
    lcnt[tid] = 0;
    __syncthreads();
    for (int j = ebeg + tid; j < eend; j += 1024) atomicAdd(&lcnt[stg[j].y - node0], 1);
    __syncthreads();
    int v = lcnt[tid];
    lscan[tid] = v;
    __syncthreads();
    for (int off = 1; off < 1024; off <<= 1) {
        int t = (tid >= off) ? lscan[tid - off] : 0;
        __syncthreads();
        lscan[tid] += t;
        __syncthreads();
    }
    int gbase = ebeg + lscan[tid] - v;
    if (node0 + tid < n) rowptr[node0 + tid] = gbase;
    lfill[tid] = gbase;
    __syncthreads();
    for (int j = ebeg + tid; j < eend; j += 1024) {
        int2 ed = stg[j];
        int p = atomicAdd(&lfill[ed.y - node0], 1);
        col[p] = ed.x;
    }
    if (b == 0 && tid == 0) rowptr[n] = e;
}

// ---- prep: fold att into W -> wal[0:64]=W@al, [64:128]=W@ar, [128]=b.al, [129]=b.ar ----
__global__ void prep_alpha_kernel(const float* __restrict__ W,
                                  const float* __restrict__ al,
                                  const float* __restrict__ ar,
                                  const float* __restrict__ B,
                                  float* __restrict__ out) {
    int t = threadIdx.x;  // 128 threads
    int k = t & 63;
    const float* att = (t >= 64) ? ar : al;
    float s = 0.f;
    for (int c = 0; c < 64; c++) s = fmaf(W[k * 64 + c], att[c], s);
    out[t] = s;
    if (t < 2) {
        const float* a2 = t ? ar : al;
        float sb = 0.f;
        for (int c = 0; c < 64; c++) sb = fmaf(B[c], a2[c], sb);
        out[128 + t] = sb;
    }
}

// ---- MFMA lin: H = bf16(X@W + b), tile = 64 nodes x 64 cols ----
template <int DIN, bool BF16IN>
__global__ __launch_bounds__(256) void lin_mfma_kernel(const void* __restrict__ Xin,
                                                       const float* __restrict__ W,
                                                       const float* __restrict__ B,
                                                       ushort* __restrict__ Hbf,
                                                       int n, int ntiles) {
    constexpr int PS = DIN + 8;
    __shared__ ushort Xl[64 * PS];
    __shared__ ushort Wt[64 * PS];  // Wt[c][k] = W[k][c]
    int tid = threadIdx.x;
    int lane = tid & 63;
    int cb = (tid >> 6) << 4;
    int colin = lane & 15, ksel = lane >> 4;
    for (int i = tid; i < DIN * 16; i += 256) {
        int k = i >> 4, cq = i & 15;
        float4 w = *(const float4*)&W[k * 64 + cq * 4];
        Wt[(cq * 4 + 0) * PS + k] = f2bf(w.x);
        Wt[(cq * 4 + 1) * PS + k] = f2bf(w.y);
        Wt[(cq * 4 + 2) * PS + k] = f2bf(w.z);
        Wt[(cq * 4 + 3) * PS + k] = f2bf(w.w);
    }
    float bc = B[cb + colin];
    for (int tile = blockIdx.x; tile < ntiles; tile += gridDim.x) {
        __syncthreads();  // guards Xl restage (and initial Wt stage)
        int node0 = tile << 6;
        if constexpr (BF16IN) {
            const ushort* Xb = (const ushort*)Xin;
            for (int i = tid; i < 64 * DIN / 8; i += 256) {
                int rr = i / (DIN / 8), ck = (i % (DIN / 8)) * 8;
                int gsrc = min(node0 + rr, n - 1);
                *(uint4*)&Xl[rr * PS + ck] = *(const uint4*)&Xb[(size_t)gsrc * DIN + ck];
            }
        } else {
            const float* Xf = (const float*)Xin;
            for (int i = tid; i < DIN * 16; i += 256) {
                int flat = i << 2;
                int rr = flat / DIN, kk = flat % DIN;
                int gsrc = min(node0 + rr, n - 1);
                float4 v = *(const float4*)&Xf[(size_t)gsrc * DIN + kk];
                ushort4 u;
                u.x = f2bf(v.x);
                u.y = f2bf(v.y);
                u.z = f2bf(v.z);
                u.w = f2bf(v.w);
                *(ushort4*)&Xl[rr * PS + kk] = u;
            }
        }
        __syncthreads();
        f32x4 acc[4];
#pragma unroll
        for (int rb = 0; rb < 4; rb++) acc[rb] = (f32x4){bc, bc, bc, bc};
#pragma unroll
        for (int ks = 0; ks < DIN; ks += 32) {
            bf16x8 bfr = *(const bf16x8*)&Wt[(cb + colin) * PS + ks + ksel * 8];
#pragma unroll
            for (int rb = 0; rb < 4; rb++) {
                bf16x8 afr = *(const bf16x8*)&Xl[(rb * 16 + colin) * PS + ks + ksel * 8];
                acc[rb] = __builtin_amdgcn_mfma_f32_16x16x32_bf16(afr, bfr, acc[rb], 0, 0, 0);
            }
        }
        // D layout: col = cb+colin, row = rb*16 + ksel*4 + r
#pragma unroll
        for (int rb = 0; rb < 4; rb++) {
#pragma unroll
            for (int r = 0; r < 4; r++) {
                int node = node0 + rb * 16 + ksel * 4 + r;
                if (node < n) Hbf[(size_t)node * 64 + cb + colin] = f2bf(acc[rb][r]);
            }
        }
    }
}

// ---- alpha (layer 0 only): 4 nodes per wave; 16-lane group = one node row ----
__global__ __launch_bounds__(256) void alpha_kernel(const ushort* __restrict__ Hbf,
                                                    const float* __restrict__ attl,
                                                    const float* __restrict__ attr,
                                                    float* __restrict__ AL,
                                                    float* __restrict__ AR, int n) {
    int wv = threadIdx.x >> 6, lane = threadIdx.x & 63;
    int g = lane >> 4, li = lane & 15;
    int node = (blockIdx.x * 4 + wv) * 4 + g;
    if (node >= n) return;
    uint2 d = *(const uint2*)((const char*)Hbf + (((size_t)node) << 7) + (li << 3));
    float4 alv = *(const float4*)&attl[li * 4];
    float4 arv = *(const float4*)&attr[li * 4];
    float h0 = bflo(d.x), h1 = bfhi(d.x), h2 = bflo(d.y), h3 = bfhi(d.y);
    float pl = h0 * alv.x + h1 * alv.y + h2 * alv.z + h3 * alv.w;
    float pr = h0 * arv.x + h1 * arv.y + h2 * arv.z + h3 * arv.w;
#pragma unroll
    for (int o = 1; o < 16; o <<= 1) {
        pl += __shfl_xor(pl, o, 64);
        pr += __shfl_xor(pr, o, 64);
    }
    if (li == 0) {
        AL[node] = pl;
        AR[node] = pr;
    }
}

// ---- AGG: 16-lane group = one node; LDS pair buffer; optional fused alpha ----
template <bool FUSEA>
__global__ __launch_bounds__(256) void agg_kernel(const int* __restrict__ rowptr,
                                                  const int* __restrict__ col,
                                                  const float* __restrict__ AL,
                                                  const float* __restrict__ AR,
                                                  const ushort* __restrict__ Hbf,
                                                  ushort* __restrict__ OUT,
                                                  const float* __restrict__ walbuf,
                                                  float* __restrict__ ALn,
                                                  float* __restrict__ ARn, int n) {
    __shared__ uint2 pairbuf[4][4][17];  // [wave][group][slot]
    int tid = threadIdx.x;
    int wv = tid >> 6, lane = tid & 63;
    int g = lane >> 4, li = lane & 15;
    int nidx = blockIdx.x * 16 + wv * 4 + g;
    bool valid = nidx < n;
    int beg = 0, deg = 0;
    float ar_i = 0.f;
    if (valid) {
        beg = rowptr[nidx];
        deg = rowptr[nidx + 1] - beg;
        ar_i = AR[nidx];
    }
    const char* hb = (const char*)Hbf + (li << 3);
    float a0 = 0.f, a1 = 0.f, a2 = 0.f, a3 = 0.f, aw = 0.f;
    for (int base = 0; base < deg; base += 16) {
        int e = base + li;
        float x = 0.f;
        int c = 0;
        if (e < deg) {
            c = col[beg + e];
            float t = AL[c] + ar_i;
            t = t > 0.f ? t : NEG_SLOPE * t;
            x = __expf(t);
        }
        pairbuf[wv][g][li] = make_uint2(__float_as_uint(x), (unsigned)c);
        int cnt = deg - base;
        if (cnt > 16) cnt = 16;
        if (cnt == 16) {
#pragma unroll
            for (int h = 0; h < 2; h++) {
                uint2 pc[8];
#pragma unroll
                for (int t = 0; t < 8; t++) pc[t] = pairbuf[wv][g][h * 8 + t];
                uint2 d[8];
#pragma unroll
                for (int t = 0; t < 8; t++)
                    d[t] = *(const uint2*)(hb + (((size_t)pc[t].y) << 7));
#pragma unroll
                for (int t = 0; t < 8; t++) {
                    float w = __uint_as_float(pc[t].x);
                    a0 = fmaf(w, bflo(d[t].x), a0);
                    a1 = fmaf(w, bfhi(d[t].x), a1);
                    a2 = fmaf(w, bflo(d[t].y), a2);
                    a3 = fmaf(w, bfhi(d[t].y), a3);
                    aw += w;
                }
            }
        } else {
            for (int t0 = 0; t0 < cnt; t0 += 4) {
                uint2 pc[4];
#pragma unroll
                for (int t = 0; t < 4; t++) {
                    int s = t0 + t;
                    pc[t] = pairbuf[wv][g][s < 16 ? s : 15];
                }
                uint2 d[4];
#pragma unroll
                for (int t = 0; t < 4; t++)
                    d[t] = *(const uint2*)(hb + (((size_t)pc[t].y) << 7));
#pragma unroll
                for (int t = 0; t < 4; t++) {
                    float w = __uint_as_float(pc[t].x);
                    a0 = fmaf(w, bflo(d[t].x), a0);
                    a1 = fmaf(w, bfhi(d[t].x), a1);
                    a2 = fmaf(w, bflo(d[t].y), a2);
                    a3 = fmaf(w, bfhi(d[t].y), a3);
                    aw += w;
                }
            }
        }
    }
    float r = 1.0f / (aw + EPS);
    float o0 = a0 * r, o1 = a1 * r, o2 = a2 * r, o3 = a3 * r;
    o0 = o0 > 0.f ? o0 : 0.f;
    o1 = o1 > 0.f ? o1 : 0.f;
    o2 = o2 > 0.f ? o2 : 0.f;
    o3 = o3 > 0.f ? o3 : 0.f;
    if (valid) {
        uint2 o;
        o.x = (unsigned int)f2bf(o0) | ((unsigned int)f2bf(o1) << 16);
        o.y = (unsigned int)f2bf(o2) | ((unsigned int)f2bf(o3) << 16);
        *(uint2*)((char*)OUT + (((size_t)nidx) << 7) + (li << 3)) = o;
    }
    if constexpr (FUSEA) {
        // next-layer alpha: relu_out . (W@att) + b.att  (8 shfl per wave total)
        float4 wl = *(const float4*)&walbuf[li * 4];
        float4 wr = *(const float4*)&walbuf[64 + li * 4];
        float pl = o0 * wl.x + o1 * wl.y + o2 * wl.z + o3 * wl.w;
        float pr = o0 * wr.x + o1 * wr.y + o2 * wr.z + o3 * wr.w;
#pragma unroll
        for (int o = 1; o < 16; o <<= 1) {
            pl += __shfl_xor(pl, o, 64);
            pr += __shfl_xor(pr, o, 64);
        }
        if (valid && li == 0) {
            ALn[nidx] = pl + walbuf[128];
            ARn[nidx] = pr + walbuf[129];
        }
    }
}

// ---- MFMA post (bf16 input): q = (h3@W1+b1)@W2+b2 ; log_softmax ----
__global__ __launch_bounds__(256) void post_mfma_kernel(const ushort* __restrict__ H3,
                                                        const float* __restrict__ Wp1,
                                                        const float* __restrict__ bp1,
                                                        const float* __restrict__ Wp2,
                                                        const float* __restrict__ bp2,
                                                        float* __restrict__ OUT,
                                                        int n, int ntiles) {
    constexpr int PS = 72;
    __shared__ ushort Hl[64 * PS];
    __shared__ ushort Pl[64 * PS];
    __shared__ ushort Wt1[64 * PS];
    __shared__ ushort Wt2[64 * PS];
    __shared__ float Ql[64 * PS];
    int tid = threadIdx.x;
    int lane = tid & 63;
    int cb = (tid >> 6) << 4;
    int colin = lane & 15, ksel = lane >> 4;
    for (int i = tid; i < 64 * 16; i += 256) {
        int k = i >> 4, cq = i & 15;
        float4 w1 = *(const float4*)&Wp1[k * 64 + cq * 4];
        Wt1[(cq * 4 + 0) * PS + k] = f2bf(w1.x);
        Wt1[(cq * 4 + 1) * PS + k] = f2bf(w1.y);
        Wt1[(cq * 4 + 2) * PS + k] = f2bf(w1.z);
        Wt1[(cq * 4 + 3) * PS + k] = f2bf(w1.w);
#pragma unroll
        for (int j = 0; j < 4; j++) {
            int c = cq * 4 + j;
            float w2 = (c < OUT_DIM) ? Wp2[k * OUT_DIM + c] : 0.f;
            Wt2[c * PS + k] = f2bf(w2);
        }
    }
    int myc = cb + colin;
    float bc1 = bp1[myc];
    float bc2 = (myc < OUT_DIM) ? bp2[myc] : 0.f;
    for (int tile = blockIdx.x; tile < ntiles; tile += gridDim.x) {
        __syncthreads();
        int node0 = tile << 6;
        for (int i = tid; i < 64 * 8; i += 256) {
            int rr = i >> 3, ck = (i & 7) << 3;
            int gsrc = min(node0 + rr, n - 1);
            *(uint4*)&Hl[rr * PS + ck] = *(const uint4*)&H3[(size_t)gsrc * 64 + ck];
        }
        __syncthreads();
        f32x4 acc1[4];
#pragma unroll
        for (int rb = 0; rb < 4; rb++) acc1[rb] = (f32x4){bc1, bc1, bc1, bc1};
#pragma unroll
        for (int ks = 0; ks < 64; ks += 32) {
            bf16x8 bfr = *(const bf16x8*)&Wt1[myc * PS + ks + ksel * 8];
#pragma unroll
            for (int rb = 0; rb < 4; rb++) {
                bf16x8 afr = *(const bf16x8*)&Hl[(rb * 16 + colin) * PS + ks + ksel * 8];
                acc1[rb] = __builtin_amdgcn_mfma_f32_16x16x32_bf16(afr, bfr, acc1[rb], 0, 0, 0);
            }
        }
#pragma unroll
        for (int rb = 0; rb < 4; rb++) {
#pragma unroll
            for (int r = 0; r < 4; r++) {
                int row = rb * 16 + ksel * 4 + r;
                Pl[row * PS + myc] = f2bf(acc1[rb][r]);
            }
        }
        __syncthreads();
        f32x4 acc2[4];
#pragma unroll
        for (int rb = 0; rb < 4; rb++) acc2[rb] = (f32x4){bc2, bc2, bc2, bc2};
#pragma unroll
        for (int ks = 0; ks < 64; ks += 32) {
            bf16x8 bfr = *(const bf16x8*)&Wt2[myc * PS + ks + ksel * 8];
#pragma unroll
            for (int rb = 0; rb < 4; rb++) {
                bf16x8 afr = *(const bf16x8*)&Pl[(rb * 16 + colin) * PS + ks + ksel * 8];
                acc2[rb] = __builtin_amdgcn_mfma_f32_16x16x32_bf16(afr, bfr, acc2[rb], 0, 0, 0);
            }
        }
#pragma unroll
        for (int rb = 0; rb < 4; rb++) {
#pragma unroll
            for (int r = 0; r < 4; r++) {
                int row = rb * 16 + ksel * 4 + r;
                Ql[row * PS + myc] = acc2[rb][r];
            }
        }
        __syncthreads();
        int nd = tid >> 2, part = tid & 3;
        int cbeg = part * 12;
        float m = -INFINITY;
#pragma unroll
        for (int i = 0; i < 12; i++) {
            int c = cbeg + i;
            if (c < OUT_DIM) m = fmaxf(m, Ql[nd * PS + c]);
        }
        m = fmaxf(m, __shfl_xor(m, 1, 64));
        m = fmaxf(m, __shfl_xor(m, 2, 64));
        float s = 0.f;
#pragma unroll
        for (int i = 0; i < 12; i++) {
            int c = cbeg + i;
            if (c < OUT_DIM) s += __expf(Ql[nd * PS + c] - m);
        }
        s += __shfl_xor(s, 1, 64);
        s += __shfl_xor(s, 2, 64);
        float lg = m + __logf(s);
        int node = node0 + nd;
        if (node < n) {
#pragma unroll
            for (int i = 0; i < 12; i++) {
                int c = cbeg + i;
                if (c < OUT_DIM) OUT[(size_t)node * OUT_DIM + c] = Ql[nd * PS + c] - lg;
            }
        }
    }
}

extern "C" void kernel_launch(void* const* d_in, const int* in_sizes, int n_in,
                              void* d_out, int out_size, void* d_ws, size_t ws_size,
                              hipStream_t stream) {
    const float* x = (const float*)d_in[0];
    const int* ei = (const int*)d_in[1];
    const float* W0 = (const float*)d_in[2];
    const float* b0 = (const float*)d_in[3];
    const float* al0 = (const float*)d_in[4];
    const float* ar0 = (const float*)d_in[5];
    const float* W1 = (const float*)d_in[6];
    const float* b1 = (const float*)d_in[7];
    const float* al1 = (const float*)d_in[8];
    const float* ar1 = (const float*)d_in[9];
    const float* W2 = (const float*)d_in[10];
    const float* b2 = (const float*)d_in[11];
    const float* al2 = (const float*)d_in[12];
    const float* ar2 = (const float*)d_in[13];
    const float* Wp1 = (const float*)d_in[14];
    const float* bp1 = (const float*)d_in[15];
    const float* Wp2 = (const float*)d_in[16];
    const float* bp2 = (const float*)d_in[17];
    float* out = (float*)d_out;

    const int N = in_sizes[0] / IN_DIM;
    const int E = in_sizes[1] / 2;
    const int NBUCK = (N + BN - 1) >> BBITS;
    const int NTILES = (N + 63) >> 6;

    char* ws = (char*)d_ws;
    ushort* HbfA = (ushort*)ws;  ws += (size_t)N * 64 * sizeof(ushort);  // lin out / agg in
    ushort* HbfB = (ushort*)ws;  ws += (size_t)N * 64 * sizeof(ushort);  // agg out / lin in
    float* ALa = (float*)ws;     ws += (size_t)N * sizeof(float);
    float* ARa = (float*)ws;     ws += (size_t)N * sizeof(float);
    float* ALc = (float*)ws;     ws += (size_t)N * sizeof(float);
    float* ARc = (float*)ws;     ws += (size_t)N * sizeof(float);
    int* rowptr = (int*)ws;      ws += (size_t)(N + 1) * sizeof(int);
    int* col = (int*)ws;         ws += (size_t)E * sizeof(int);
    int* bcnt = (int*)ws;        ws += (size_t)NBUCK * sizeof(int);
    int* bbase = (int*)ws;       ws += (size_t)(NBUCK + 1) * sizeof(int);
    int* bfill = (int*)ws;       ws += (size_t)NBUCK * sizeof(int);
    float* walb1 = (float*)ws;   ws += 256 * sizeof(float);
    float* walb2 = (float*)ws;   ws += 256 * sizeof(float);
    int2* stg = (int2*)ws;       ws += (size_t)E * sizeof(int2);

    const int* src = ei;
    const int* dst = ei + E;

    // ---- CSR build + folded-alpha prep ----
    hipMemsetAsync(bcnt, 0, (size_t)NBUCK * sizeof(int), stream);
    prep_alpha_kernel<<<1, 128, 0, stream>>>(W1, al1, ar1, b1, walb1);
    prep_alpha_kernel<<<1, 128, 0, stream>>>(W2, al2, ar2, b2, walb2);
    bucket_count_kernel<<<1024, 256, 0, stream>>>(dst, bcnt, E, NBUCK);
    bucket_scan_kernel<<<1, 64, 0, stream>>>(bcnt, bbase, bfill, NBUCK);
    bucket_scatter_kernel<<<1024, 256, 0, stream>>>(src, dst, bfill, stg, E, NBUCK);
    bucket_place_kernel<<<NBUCK, 1024, 0, stream>>>(stg, bbase, rowptr, col, N, E);

    int agg_grid = (N + 15) / 16;
    int alpha_grid = (N + 15) / 16;

    // ---- layer 0 ----
    lin_mfma_kernel<IN_DIM, false><<<512, 256, 0, stream>>>(x, W0, b0, HbfA, N, NTILES);
    alpha_kernel<<<alpha_grid, 256, 0, stream>>>(HbfA, al0, ar0, ALa, ARa, N);
    agg_kernel<true><<<agg_grid, 256, 0, stream>>>(rowptr, col, ALa, ARa, HbfA, HbfB,
                                                   walb1, ALc, ARc, N);
    // ---- layer 1 (alpha fused into previous agg) ----
    lin_mfma_kernel<HID, true><<<512, 256, 0, stream>>>(HbfB, W1, b1, HbfA, N, NTILES);
    agg_kernel<true><<<agg_grid, 256, 0, stream>>>(rowptr, col, ALc, ARc, HbfA, HbfB,
                                                   walb2, ALa, ARa, N);
    // ---- layer 2 ----
    lin_mfma_kernel<HID, true><<<512, 256, 0, stream>>>(HbfB, W2, b2, HbfA, N, NTILES);
    agg_kernel<false><<<agg_grid, 256, 0, stream>>>(rowptr, col, ALa, ARa, HbfA, HbfB,
                                                    nullptr, nullptr, nullptr, N);
    // ---- post ----
    post_mfma_kernel<<<512, 256, 0, stream>>>(HbfB, Wp1, bp1, Wp2, bp2, out, N, NTILES);
}

// Round 13
// 250.191 us; speedup vs baseline: 1.2007x; 1.2007x over previous
//
#include <hip/hip_runtime.h>
#include <hip/hip_bf16.h>
#include <math.h>

// GNNStack: 3x GAT(heads=1, hid=64) + relu, then 64->64, 64->47, log_softmax.
//  - CSR build: two-level counting sort. R13: scatter back to 256 blocks
//    (R12: 1024 blocks shrank runs -> +50% write amp, slower). Batched
//    8-wide edge processing (breaks the load->LDSatomic->store dependent
//    chain, which limits at VALUBusy 1.2%), stg packed to 4B
//    ((dst&1023)<<22 | src) halving scatter writes + place reads.
//  - LIN/POST: MFMA 16x16x32 bf16, all inter-layer tensors bf16.
//  - alpha layers 1,2 fused into agg epilogue (folded W@att vectors).
//  - AGG: 16-lane group = one node; LDS pair buffer; 8-deep gather batches.

#define IN_DIM 128
#define HID 64
#define OUT_DIM 47
#define NEG_SLOPE 0.2f
#define EPS 1e-16f
#define BBITS 10
#define BN 1024
#define NBUCK_MAX 128
#define SRCMASK 0x3FFFFF

typedef short bf16x8 __attribute__((ext_vector_type(8)));
typedef float f32x4 __attribute__((ext_vector_type(4)));

__device__ __forceinline__ float bflo(unsigned int d) {
    union { unsigned int i; float f; } c;
    c.i = d << 16;
    return c.f;
}
__device__ __forceinline__ float bfhi(unsigned int d) {
    union { unsigned int i; float f; } c;
    c.i = d & 0xffff0000u;
    return c.f;
}
__device__ __forceinline__ ushort f2bf(float f) {
    __hip_bfloat16 b = __float2bfloat16(f);
    return *(ushort*)&b;
}

// ---- CSR build ----
__global__ __launch_bounds__(256) void bucket_count_kernel(const int* __restrict__ dst,
                                                           int* __restrict__ bcnt,
                                                           int e, int nbuck) {
    __shared__ int h[NBUCK_MAX];
    int tid = threadIdx.x;
    if (tid < nbuck) h[tid] = 0;
    __syncthreads();
    int chunk = (e + gridDim.x - 1) / gridDim.x;
    int beg = blockIdx.x * chunk, end = min(e, beg + chunk);
    int i = beg + tid;
    for (; i + 7 * 256 < end; i += 8 * 256) {
        int b[8];
#pragma unroll
        for (int t = 0; t < 8; t++) b[t] = dst[i + t * 256] >> BBITS;
#pragma unroll
        for (int t = 0; t < 8; t++) atomicAdd(&h[b[t]], 1);
    }
    for (; i < end; i += 256) atomicAdd(&h[dst[i] >> BBITS], 1);
    __syncthreads();
    if (tid < nbuck && h[tid]) atomicAdd(&bcnt[tid], h[tid]);
}

__global__ void bucket_scan_kernel(const int* __restrict__ bcnt, int* __restrict__ bbase,
                                   int* __restrict__ bfill, int nbuck) {
    if (threadIdx.x == 0 && blockIdx.x == 0) {
        int run = 0;
        for (int i = 0; i < nbuck; i++) { bbase[i] = run; bfill[i] = run; run += bcnt[i]; }
        bbase[nbuck] = run;
    }
}

__global__ __launch_bounds__(256) void bucket_scatter_kernel(const int* __restrict__ src,
                                                             const int* __restrict__ dst,
                                                             int* __restrict__ bfill,
                                                             unsigned* __restrict__ stg,
                                                             int e, int nbuck) {
    __shared__ int lcnt[NBUCK_MAX], lfill[NBUCK_MAX];
    int tid = threadIdx.x;
    if (tid < nbuck) lcnt[tid] = 0;
    __syncthreads();
    int chunk = (e + gridDim.x - 1) / gridDim.x;
    int beg = blockIdx.x * chunk, end = min(e, beg + chunk);
    // pass 1: block histogram (batched)
    int i = beg + tid;
    for (; i + 7 * 256 < end; i += 8 * 256) {
        int b[8];
#pragma unroll
        for (int t = 0; t < 8; t++) b[t] = dst[i + t * 256] >> BBITS;
#pragma unroll
        for (int t = 0; t < 8; t++) atomicAdd(&lcnt[b[t]], 1);
    }
    for (; i < end; i += 256) atomicAdd(&lcnt[dst[i] >> BBITS], 1);
    __syncthreads();
    if (tid < nbuck) lfill[tid] = lcnt[tid] ? atomicAdd(&bfill[tid], lcnt[tid]) : 0;
    __syncthreads();
    // pass 2: batched scatter (8 independent atomic->store chains per lane)
    i = beg + tid;
    for (; i + 7 * 256 < end; i += 8 * 256) {
        int d[8], s[8];
#pragma unroll
        for (int t = 0; t < 8; t++) {
            d[t] = dst[i + t * 256];
            s[t] = src[i + t * 256];
        }
        int p[8];
#pragma unroll
        for (int t = 0; t < 8; t++) p[t] = atomicAdd(&lfill[d[t] >> BBITS], 1);
#pragma unroll
        for (int t = 0; t < 8; t++)
            stg[p[t]] = ((unsigned)(d[t] & (BN - 1)) << 22) | (unsigned)s[t];
    }
    for (; i < end; i += 256) {
        int d = dst[i];
        int p = atomicAdd(&lfill[d >> BBITS], 1);
        stg[p] = ((unsigned)(d & (BN - 1)) << 22) | (unsigned)src[i];
    }
}

__global__ __launch_bounds__(1024) void bucket_place_kernel(const unsigned* __restrict__ stg,
                                                            const int* __restrict__ bbase,
                                                            int* __restrict__ rowptr,
                                                            int* __restrict__ col,
                                                            int n, int e) {
    __shared__ int lcnt[BN];
    __shared__ int lscan[BN];
    __shared__ int lfill[BN];
    int tid = threadIdx.x, b = blockIdx.x;
    int node0 = b << BBITS;
    int ebeg = bbase[b], eend = bbase[b + 1];
    lcnt[tid] = 0;
    __syncthreads();
    for (int j = ebeg + tid; j < eend; j += 1024) atomicAdd(&lcnt[stg[j] >> 22], 1);
    __syncthreads();
    int v = lcnt[tid];
    lscan[tid] = v;
    __syncthreads();
    for (int off = 1; off < 1024; off <<= 1) {
        int t = (tid >= off) ? lscan[tid - off] : 0;
        __syncthreads();
        lscan[tid] += t;
        __syncthreads();
    }
    int gbase = ebeg + lscan[tid] - v;
    if (node0 + tid < n) rowptr[node0 + tid] = gbase;
    lfill[tid] = gbase;
    __syncthreads();
    for (int j = ebeg + tid; j < eend; j += 1024) {
        unsigned ed = stg[j];
        int p = atomicAdd(&lfill[ed >> 22], 1);
        col[p] = (int)(ed & SRCMASK);
    }
    if (b == 0 && tid == 0) rowptr[n] = e;
}

// ---- prep: fold att into W -> wal[0:64]=W@al, [64:128]=W@ar, [128]=b.al, [129]=b.ar ----
__global__ void prep_alpha_kernel(const float* __restrict__ W,
                                  const float* __restrict__ al,
                                  const float* __restrict__ ar,
                                  const float* __restrict__ B,
                                  float* __restrict__ out) {
    int t = threadIdx.x;  // 128 threads
    int k = t & 63;
    const float* att = (t >= 64) ? ar : al;
    float s = 0.f;
    for (int c = 0; c < 64; c++) s = fmaf(W[k * 64 + c], att[c], s);
    out[t] = s;
    if (t < 2) {
        const float* a2 = t ? ar : al;
        float sb = 0.f;
        for (int c = 0; c < 64; c++) sb = fmaf(B[c], a2[c], sb);
        out[128 + t] = sb;
    }
}

// ---- MFMA lin: H = bf16(X@W + b), tile = 64 nodes x 64 cols ----
template <int DIN, bool BF16IN>
__global__ __launch_bounds__(256) void lin_mfma_kernel(const void* __restrict__ Xin,
                                                       const float* __restrict__ W,
                                                       const float* __restrict__ B,
                                                       ushort* __restrict__ Hbf,
                                                       int n, int ntiles) {
    constexpr int PS = DIN + 8;
    __shared__ ushort Xl[64 * PS];
    __shared__ ushort Wt[64 * PS];  // Wt[c][k] = W[k][c]
    int tid = threadIdx.x;
    int lane = tid & 63;
    int cb = (tid >> 6) << 4;
    int colin = lane & 15, ksel = lane >> 4;
    for (int i = tid; i < DIN * 16; i += 256) {
        int k = i >> 4, cq = i & 15;
        float4 w = *(const float4*)&W[k * 64 + cq * 4];
        Wt[(cq * 4 + 0) * PS + k] = f2bf(w.x);
        Wt[(cq * 4 + 1) * PS + k] = f2bf(w.y);
        Wt[(cq * 4 + 2) * PS + k] = f2bf(w.z);
        Wt[(cq * 4 + 3) * PS + k] = f2bf(w.w);
    }
    float bc = B[cb + colin];
    for (int tile = blockIdx.x; tile < ntiles; tile += gridDim.x) {
        __syncthreads();  // guards Xl restage (and initial Wt stage)
        int node0 = tile << 6;
        if constexpr (BF16IN) {
            const ushort* Xb = (const ushort*)Xin;
            for (int i = tid; i < 64 * DIN / 8; i += 256) {
                int rr = i / (DIN / 8), ck = (i % (DIN / 8)) * 8;
                int gsrc = min(node0 + rr, n - 1);
                *(uint4*)&Xl[rr * PS + ck] = *(const uint4*)&Xb[(size_t)gsrc * DIN + ck];
            }
        } else {
            const float* Xf = (const float*)Xin;
            for (int i = tid; i < DIN * 16; i += 256) {
                int flat = i << 2;
                int rr = flat / DIN, kk = flat % DIN;
                int gsrc = min(node0 + rr, n - 1);
                float4 v = *(const float4*)&Xf[(size_t)gsrc * DIN + kk];
                ushort4 u;
                u.x = f2bf(v.x);
                u.y = f2bf(v.y);
                u.z = f2bf(v.z);
                u.w = f2bf(v.w);
                *(ushort4*)&Xl[rr * PS + kk] = u;
            }
        }
        __syncthreads();
        f32x4 acc[4];
#pragma unroll
        for (int rb = 0; rb < 4; rb++) acc[rb] = (f32x4){bc, bc, bc, bc};
#pragma unroll
        for (int ks = 0; ks < DIN; ks += 32) {
            bf16x8 bfr = *(const bf16x8*)&Wt[(cb + colin) * PS + ks + ksel * 8];
#pragma unroll
            for (int rb = 0; rb < 4; rb++) {
                bf16x8 afr = *(const bf16x8*)&Xl[(rb * 16 + colin) * PS + ks + ksel * 8];
                acc[rb] = __builtin_amdgcn_mfma_f32_16x16x32_bf16(afr, bfr, acc[rb], 0, 0, 0);
            }
        }
        // D layout: col = cb+colin, row = rb*16 + ksel*4 + r
#pragma unroll
        for (int rb = 0; rb < 4; rb++) {
#pragma unroll
            for (int r = 0; r < 4; r++) {
                int node = node0 + rb * 16 + ksel * 4 + r;
                if (node < n) Hbf[(size_t)node * 64 + cb + colin] = f2bf(acc[rb][r]);
            }
        }
    }
}

// ---- alpha (layer 0 only): 4 nodes per wave; 16-lane group = one node row ----
__global__ __launch_bounds__(256) void alpha_kernel(const ushort* __restrict__ Hbf,
                                                    const float* __restrict__ attl,
                                                    const float* __restrict__ attr,
                                                    float* __restrict__ AL,
                                                    float* __restrict__ AR, int n) {
    int wv = threadIdx.x >> 6, lane = threadIdx.x & 63;
    int g = lane >> 4, li = lane & 15;
    int node = (blockIdx.x * 4 + wv) * 4 + g;
    if (node >= n) return;
    uint2 d = *(const uint2*)((const char*)Hbf + (((size_t)node) << 7) + (li << 3));
    float4 alv = *(const float4*)&attl[li * 4];
    float4 arv = *(const float4*)&attr[li * 4];
    float h0 = bflo(d.x), h1 = bfhi(d.x), h2 = bflo(d.y), h3 = bfhi(d.y);
    float pl = h0 * alv.x + h1 * alv.y + h2 * alv.z + h3 * alv.w;
    float pr = h0 * arv.x + h1 * arv.y + h2 * arv.z + h3 * arv.w;
#pragma unroll
    for (int o = 1; o < 16; o <<= 1) {
        pl += __shfl_xor(pl, o, 64);
        pr += __shfl_xor(pr, o, 64);
    }
    if (li == 0) {
        AL[node] = pl;
        AR[node] = pr;
    }
}

// ---- AGG: 16-lane group = one node; LDS pair buffer; optional fused alpha ----
template <bool FUSEA>
__global__ __launch_bounds__(256) void agg_kernel(const int* __restrict__ rowptr,
                                                  const int* __restrict__ col,
                                                  const float* __restrict__ AL,
                                                  const float* __restrict__ AR,
                                                  const ushort* __restrict__ Hbf,
                                                  ushort* __restrict__ OUT,
                                                  const float* __restrict__ walbuf,
                                                  float* __restrict__ ALn,
                                                  float* __restrict__ ARn, int n) {
    __shared__ uint2 pairbuf[4][4][17];  // [wave][group][slot]
    int tid = threadIdx.x;
    int wv = tid >> 6, lane = tid & 63;
    int g = lane >> 4, li = lane & 15;
    int nidx = blockIdx.x * 16 + wv * 4 + g;
    bool valid = nidx < n;
    int beg = 0, deg = 0;
    float ar_i = 0.f;
    if (valid) {
        beg = rowptr[nidx];
        deg = rowptr[nidx + 1] - beg;
        ar_i = AR[nidx];
    }
    const char* hb = (const char*)Hbf + (li << 3);
    float a0 = 0.f, a1 = 0.f, a2 = 0.f, a3 = 0.f, aw = 0.f;
    for (int base = 0; base < deg; base += 16) {
        int e = base + li;
        float x = 0.f;
        int c = 0;
        if (e < deg) {
            c = col[beg + e];
            float t = AL[c] + ar_i;
            t = t > 0.f ? t : NEG_SLOPE * t;
            x = __expf(t);
        }
        pairbuf[wv][g][li] = make_uint2(__float_as_uint(x), (unsigned)c);
        int cnt = deg - base;
        if (cnt > 16) cnt = 16;
        if (cnt == 16) {
#pragma unroll
            for (int h = 0; h < 2; h++) {
                uint2 pc[8];
#pragma unroll
                for (int t = 0; t < 8; t++) pc[t] = pairbuf[wv][g][h * 8 + t];
                uint2 d[8];
#pragma unroll
                for (int t = 0; t < 8; t++)
                    d[t] = *(const uint2*)(hb + (((size_t)pc[t].y) << 7));
#pragma unroll
                for (int t = 0; t < 8; t++) {
                    float w = __uint_as_float(pc[t].x);
                    a0 = fmaf(w, bflo(d[t].x), a0);
                    a1 = fmaf(w, bfhi(d[t].x), a1);
                    a2 = fmaf(w, bflo(d[t].y), a2);
                    a3 = fmaf(w, bfhi(d[t].y), a3);
                    aw += w;
                }
            }
        } else {
            for (int t0 = 0; t0 < cnt; t0 += 4) {
                uint2 pc[4];
#pragma unroll
                for (int t = 0; t < 4; t++) {
                    int s = t0 + t;
                    pc[t] = pairbuf[wv][g][s < 16 ? s : 15];
                }
                uint2 d[4];
#pragma unroll
                for (int t = 0; t < 4; t++)
                    d[t] = *(const uint2*)(hb + (((size_t)pc[t].y) << 7));
#pragma unroll
                for (int t = 0; t < 4; t++) {
                    float w = __uint_as_float(pc[t].x);
                    a0 = fmaf(w, bflo(d[t].x), a0);
                    a1 = fmaf(w, bfhi(d[t].x), a1);
                    a2 = fmaf(w, bflo(d[t].y), a2);
                    a3 = fmaf(w, bfhi(d[t].y), a3);
                    aw += w;
                }
            }
        }
    }
    float r = 1.0f / (aw + EPS);
    float o0 = a0 * r, o1 = a1 * r, o2 = a2 * r, o3 = a3 * r;
    o0 = o0 > 0.f ? o0 : 0.f;
    o1 = o1 > 0.f ? o1 : 0.f;
    o2 = o2 > 0.f ? o2 : 0.f;
    o3 = o3 > 0.f ? o3 : 0.f;
    if (valid) {
        uint2 o;
        o.x = (unsigned int)f2bf(o0) | ((unsigned int)f2bf(o1) << 16);
        o.y = (unsigned int)f2bf(o2) | ((unsigned int)f2bf(o3) << 16);
        *(uint2*)((char*)OUT + (((size_t)nidx) << 7) + (li << 3)) = o;
    }
    if constexpr (FUSEA) {
        float4 wl = *(const float4*)&walbuf[li * 4];
        float4 wr = *(const float4*)&walbuf[64 + li * 4];
        float pl = o0 * wl.x + o1 * wl.y + o2 * wl.z + o3 * wl.w;
        float pr = o0 * wr.x + o1 * wr.y + o2 * wr.z + o3 * wr.w;
#pragma unroll
        for (int o = 1; o < 16; o <<= 1) {
            pl += __shfl_xor(pl, o, 64);
            pr += __shfl_xor(pr, o, 64);
        }
        if (valid && li == 0) {
            ALn[nidx] = pl + walbuf[128];
            ARn[nidx] = pr + walbuf[129];
        }
    }
}

// ---- MFMA post (bf16 input): q = (h3@W1+b1)@W2+b2 ; log_softmax ----
__global__ __launch_bounds__(256) void post_mfma_kernel(const ushort* __restrict__ H3,
                                                        const float* __restrict__ Wp1,
                                                        const float* __restrict__ bp1,
                                                        const float* __restrict__ Wp2,
                                                        const float* __restrict__ bp2,
                                                        float* __restrict__ OUT,
                                                        int n, int ntiles) {
    constexpr int PS = 72;
    __shared__ ushort Hl[64 * PS];
    __shared__ ushort Pl[64 * PS];
    __shared__ ushort Wt1[64 * PS];
    __shared__ ushort Wt2[64 * PS];
    __shared__ float Ql[64 * PS];
    int tid = threadIdx.x;
    int lane = tid & 63;
    int cb = (tid >> 6) << 4;
    int colin = lane & 15, ksel = lane >> 4;
    for (int i = tid; i < 64 * 16; i += 256) {
        int k = i >> 4, cq = i & 15;
        float4 w1 = *(const float4*)&Wp1[k * 64 + cq * 4];
        Wt1[(cq * 4 + 0) * PS + k] = f2bf(w1.x);
        Wt1[(cq * 4 + 1) * PS + k] = f2bf(w1.y);
        Wt1[(cq * 4 + 2) * PS + k] = f2bf(w1.z);
        Wt1[(cq * 4 + 3) * PS + k] = f2bf(w1.w);
#pragma unroll
        for (int j = 0; j < 4; j++) {
            int c = cq * 4 + j;
            float w2 = (c < OUT_DIM) ? Wp2[k * OUT_DIM + c] : 0.f;
            Wt2[c * PS + k] = f2bf(w2);
        }
    }
    int myc = cb + colin;
    float bc1 = bp1[myc];
    float bc2 = (myc < OUT_DIM) ? bp2[myc] : 0.f;
    for (int tile = blockIdx.x; tile < ntiles; tile += gridDim.x) {
        __syncthreads();
        int node0 = tile << 6;
        for (int i = tid; i < 64 * 8; i += 256) {
            int rr = i >> 3, ck = (i & 7) << 3;
            int gsrc = min(node0 + rr, n - 1);
            *(uint4*)&Hl[rr * PS + ck] = *(const uint4*)&H3[(size_t)gsrc * 64 + ck];
        }
        __syncthreads();
        f32x4 acc1[4];
#pragma unroll
        for (int rb = 0; rb < 4; rb++) acc1[rb] = (f32x4){bc1, bc1, bc1, bc1};
#pragma unroll
        for (int ks = 0; ks < 64; ks += 32) {
            bf16x8 bfr = *(const bf16x8*)&Wt1[myc * PS + ks + ksel * 8];
#pragma unroll
            for (int rb = 0; rb < 4; rb++) {
                bf16x8 afr = *(const bf16x8*)&Hl[(rb * 16 + colin) * PS + ks + ksel * 8];
                acc1[rb] = __builtin_amdgcn_mfma_f32_16x16x32_bf16(afr, bfr, acc1[rb], 0, 0, 0);
            }
        }
#pragma unroll
        for (int rb = 0; rb < 4; rb++) {
#pragma unroll
            for (int r = 0; r < 4; r++) {
                int row = rb * 16 + ksel * 4 + r;
                Pl[row * PS + myc] = f2bf(acc1[rb][r]);
            }
        }
        __syncthreads();
        f32x4 acc2[4];
#pragma unroll
        for (int rb = 0; rb < 4; rb++) acc2[rb] = (f32x4){bc2, bc2, bc2, bc2};
#pragma unroll
        for (int ks = 0; ks < 64; ks += 32) {
            bf16x8 bfr = *(const bf16x8*)&Wt2[myc * PS + ks + ksel * 8];
#pragma unroll
            for (int rb = 0; rb < 4; rb++) {
                bf16x8 afr = *(const bf16x8*)&Pl[(rb * 16 + colin) * PS + ks + ksel * 8];
                acc2[rb] = __builtin_amdgcn_mfma_f32_16x16x32_bf16(afr, bfr, acc2[rb], 0, 0, 0);
            }
        }
#pragma unroll
        for (int rb = 0; rb < 4; rb++) {
#pragma unroll
            for (int r = 0; r < 4; r++) {
                int row = rb * 16 + ksel * 4 + r;
                Ql[row * PS + myc] = acc2[rb][r];
            }
        }
        __syncthreads();
        int nd = tid >> 2, part = tid & 3;
        int cbeg = part * 12;
        float m = -INFINITY;
#pragma unroll
        for (int i = 0; i < 12; i++) {
            int c = cbeg + i;
            if (c < OUT_DIM) m = fmaxf(m, Ql[nd * PS + c]);
        }
        m = fmaxf(m, __shfl_xor(m, 1, 64));
        m = fmaxf(m, __shfl_xor(m, 2, 64));
        float s = 0.f;
#pragma unroll
        for (int i = 0; i < 12; i++) {
            int c = cbeg + i;
            if (c < OUT_DIM) s += __expf(Ql[nd * PS + c] - m);
        }
        s += __shfl_xor(s, 1, 64);
        s += __shfl_xor(s, 2, 64);
        float lg = m + __logf(s);
        int node = node0 + nd;
        if (node < n) {
#pragma unroll
            for (int i = 0; i < 12; i++) {
                int c = cbeg + i;
                if (c < OUT_DIM) OUT[(size_t)node * OUT_DIM + c] = Ql[nd * PS + c] - lg;
            }
        }
    }
}

extern "C" void kernel_launch(void* const* d_in, const int* in_sizes, int n_in,
                              void* d_out, int out_size, void* d_ws, size_t ws_size,
                              hipStream_t stream) {
    const float* x = (const float*)d_in[0];
    const int* ei = (const int*)d_in[1];
    const float* W0 = (const float*)d_in[2];
    const float* b0 = (const float*)d_in[3];
    const float* al0 = (const float*)d_in[4];
    const float* ar0 = (const float*)d_in[5];
    const float* W1 = (const float*)d_in[6];
    const float* b1 = (const float*)d_in[7];
    const float* al1 = (const float*)d_in[8];
    const float* ar1 = (const float*)d_in[9];
    const float* W2 = (const float*)d_in[10];
    const float* b2 = (const float*)d_in[11];
    const float* al2 = (const float*)d_in[12];
    const float* ar2 = (const float*)d_in[13];
    const float* Wp1 = (const float*)d_in[14];
    const float* bp1 = (const float*)d_in[15];
    const float* Wp2 = (const float*)d_in[16];
    const float* bp2 = (const float*)d_in[17];
    float* out = (float*)d_out;

    const int N = in_sizes[0] / IN_DIM;
    const int E = in_sizes[1] / 2;
    const int NBUCK = (N + BN - 1) >> BBITS;
    const int NTILES = (N + 63) >> 6;

    char* ws = (char*)d_ws;
    ushort* HbfA = (ushort*)ws;  ws += (size_t)N * 64 * sizeof(ushort);  // lin out / agg in
    ushort* HbfB = (ushort*)ws;  ws += (size_t)N * 64 * sizeof(ushort);  // agg out / lin in
    float* ALa = (float*)ws;     ws += (size_t)N * sizeof(float);
    float* ARa = (float*)ws;     ws += (size_t)N * sizeof(float);
    float* ALc = (float*)ws;     ws += (size_t)N * sizeof(float);
    float* ARc = (float*)ws;     ws += (size_t)N * sizeof(float);
    int* rowptr = (int*)ws;      ws += (size_t)(N + 1) * sizeof(int);
    int* col = (int*)ws;         ws += (size_t)E * sizeof(int);
    int* bcnt = (int*)ws;        ws += (size_t)NBUCK * sizeof(int);
    int* bbase = (int*)ws;       ws += (size_t)(NBUCK + 1) * sizeof(int);
    int* bfill = (int*)ws;       ws += (size_t)NBUCK * sizeof(int);
    float* walb1 = (float*)ws;   ws += 256 * sizeof(float);
    float* walb2 = (float*)ws;   ws += 256 * sizeof(float);
    unsigned* stg = (unsigned*)ws;  ws += (size_t)E * sizeof(unsigned);

    const int* src = ei;
    const int* dst = ei + E;

    // ---- CSR build + folded-alpha prep ----
    hipMemsetAsync(bcnt, 0, (size_t)NBUCK * sizeof(int), stream);
    prep_alpha_kernel<<<1, 128, 0, stream>>>(W1, al1, ar1, b1, walb1);
    prep_alpha_kernel<<<1, 128, 0, stream>>>(W2, al2, ar2, b2, walb2);
    bucket_count_kernel<<<256, 256, 0, stream>>>(dst, bcnt, E, NBUCK);
    bucket_scan_kernel<<<1, 64, 0, stream>>>(bcnt, bbase, bfill, NBUCK);
    bucket_scatter_kernel<<<256, 256, 0, stream>>>(src, dst, bfill, stg, E, NBUCK);
    bucket_place_kernel<<<NBUCK, 1024, 0, stream>>>(stg, bbase, rowptr, col, N, E);

    int agg_grid = (N + 15) / 16;
    int alpha_grid = (N + 15) / 16;

    // ---- layer 0 ----
    lin_mfma_kernel<IN_DIM, false><<<512, 256, 0, stream>>>(x, W0, b0, HbfA, N, NTILES);
    alpha_kernel<<<alpha_grid, 256, 0, stream>>>(HbfA, al0, ar0, ALa, ARa, N);
    agg_kernel<true><<<agg_grid, 256, 0, stream>>>(rowptr, col, ALa, ARa, HbfA, HbfB,
                                                   walb1, ALc, ARc, N);
    // ---- layer 1 (alpha fused into previous agg) ----
    lin_mfma_kernel<HID, true><<<512, 256, 0, stream>>>(HbfB, W1, b1, HbfA, N, NTILES);
    agg_kernel<true><<<agg_grid, 256, 0, stream>>>(rowptr, col, ALc, ARc, HbfA, HbfB,
                                                   walb2, ALa, ARa, N);
    // ---- layer 2 ----
    lin_mfma_kernel<HID, true><<<512, 256, 0, stream>>>(HbfB, W2, b2, HbfA, N, NTILES);
    agg_kernel<false><<<agg_grid, 256, 0, stream>>>(rowptr, col, ALa, ARa, HbfA, HbfB,
                                                    nullptr, nullptr, nullptr, N);
    // ---- post ----
    post_mfma_kernel<<<512, 256, 0, stream>>>(HbfB, Wp1, bp1, Wp2, bp2, out, N, NTILES);
}